// Round 17
// baseline (1165.800 us; speedup 1.0000x reference)
//
#include <hip/hip_runtime.h>
#include <stdint.h>

#define DEPTH 4
#define BATCH 8
#define NN 2048
#define ZDIM 512
#define SDIM 64
#define MLPD 2048
#define ROWS (BATCH*NN)   // 16384

typedef __bf16 bf16x8_t __attribute__((ext_vector_type(8)));
typedef float f32x4_t __attribute__((ext_vector_type(4)));
typedef unsigned short us;

#define AS1 __attribute__((address_space(1)))
#define AS3 __attribute__((address_space(3)))

__device__ __forceinline__ void gload16(const void* g, void* l) {
  __builtin_amdgcn_global_load_lds((const AS1 void*)g, (AS3 void*)l, 16, 0, 0);
}

__device__ __forceinline__ unsigned short f2bf(float f) {
  union { float f; unsigned u; } v; v.f = f;
  unsigned u = v.u;
  unsigned r = (u + 0x7fffu + ((u >> 16) & 1u)) >> 16;
  return (unsigned short)r;
}
__device__ __forceinline__ float bf2f(unsigned short h) {
  union { unsigned u; float f; } v; v.u = ((unsigned)h) << 16;
  return v.f;
}

// tanh-form GELU
__device__ __forceinline__ float gelu_fast(float x) {
  float x2 = x * x;
  float q = fmaf(x2, -0.0713548162f, -1.5957691216f);
  float em = __expf(q * x);
  return x * __builtin_amdgcn_rcpf(1.0f + em);
}

#define LGKM0() do { asm volatile("s_waitcnt lgkmcnt(0)" ::: "memory"); \
                     __builtin_amdgcn_sched_barrier(0); } while (0)
#define MF(A_, B_, C_) __builtin_amdgcn_mfma_f32_16x16x32_bf16(A_, B_, C_, 0, 0, 0)

// ---- convert spatial embedding rows to bf16 + squared norms ------------------
__global__ __launch_bounds__(256) void conv_e_kernel(const float* __restrict__ s,
    unsigned short* __restrict__ ebf, float* __restrict__ sq) {
  int lane = threadIdx.x & 63;
  int row = blockIdx.x * 4 + (threadIdx.x >> 6);
  float x = s[(long)row * SDIM + lane];
  unsigned short v = f2bf(x);
  ebf[(long)row * SDIM + lane] = v;
  float xb = bf2f(v);
  float ss = xb * xb;
  #pragma unroll
  for (int off = 32; off > 0; off >>= 1) ss += __shfl_xor(ss, off);
  if (lane == 0) sq[row] = ss;
}

// ---- transpose + f32->bf16 ---------------------------------------------------
__global__ __launch_bounds__(256) void tconv_kernel(const float* __restrict__ in,
    unsigned short* __restrict__ out, int R, int C, long sIn, long sOut) {
  __shared__ float tile[32][33];
  int b = blockIdx.z;
  int c0 = blockIdx.x * 32, r0 = blockIdx.y * 32;
  int tx = threadIdx.x, ty = threadIdx.y;
  const float* ib = in + (long)b * sIn;
  unsigned short* ob = out + (long)b * sOut;
  #pragma unroll
  for (int i = 0; i < 32; i += 8)
    tile[ty + i][tx] = ib[(long)(r0 + ty + i) * C + c0 + tx];
  __syncthreads();
  #pragma unroll
  for (int i = 0; i < 32; i += 8)
    ob[(long)(c0 + ty + i) * R + r0 + tx] = f2bf(tile[tx][ty + i]);
}

// ---- LayerNorm over D=512 ----------------------------------------------------
__global__ __launch_bounds__(256) void ln_kernel(const float* __restrict__ x,
    const float* __restrict__ scale, const float* __restrict__ bias,
    unsigned short* __restrict__ y) {
  int lane = threadIdx.x & 63;
  long row = (long)blockIdx.x * 4 + (threadIdx.x >> 6);
  const float* xr = x + row * ZDIM + lane * 8;
  float4 v0 = *(const float4*)xr;
  float4 v1 = *(const float4*)(xr + 4);
  float xv[8] = {v0.x, v0.y, v0.z, v0.w, v1.x, v1.y, v1.z, v1.w};
  float s1 = 0.f, s2 = 0.f;
  #pragma unroll
  for (int k = 0; k < 8; ++k) { s1 += xv[k]; s2 += xv[k] * xv[k]; }
  #pragma unroll
  for (int off = 32; off > 0; off >>= 1) {
    s1 += __shfl_xor(s1, off);
    s2 += __shfl_xor(s2, off);
  }
  float mean = s1 * (1.0f / ZDIM);
  float var = s2 * (1.0f / ZDIM) - mean * mean;
  float rstd = rsqrtf(var + 1e-5f);
  const float* sc = scale + lane * 8;
  const float* bi = bias + lane * 8;
  alignas(16) unsigned short o[8];
  #pragma unroll
  for (int k = 0; k < 8; ++k)
    o[k] = f2bf((xv[k] - mean) * rstd * sc[k] + bi[k]);
  *(uint4*)(y + row * ZDIM + lane * 8) = *(const uint4*)o;
}

// ---- attention weights, 8-way j-split ----------------------------------------
__global__ __launch_bounds__(256) void attn_w_kernel(const unsigned short* __restrict__ ebf,
    const float* __restrict__ sq, unsigned short* __restrict__ wout,
    float* __restrict__ RS) {
  __shared__ unsigned short Ei[4096];
  __shared__ unsigned short Ej[8192];
  __shared__ unsigned short Wt[8192];
  int tid = threadIdx.x, lane = tid & 63, wid = tid >> 6;
  int lr = lane & 15, hi = lane >> 4;
  int q = blockIdx.y;
  int b = blockIdx.z;
  int i0 = blockIdx.x * 64;
  const unsigned short* eb = ebf + (long)b * NN * SDIM;

  int rl = tid >> 3;
  int scs = ((tid & 7) ^ (rl & 7)) * 8;
  int dstc = (tid & 192) * 8;

  #pragma unroll
  for (int it = 0; it < 2; ++it)
    gload16(eb + (long)(i0 + it * 32 + rl) * SDIM + scs, &Ei[it * 2048 + dstc]);
  #pragma unroll
  for (int it = 0; it < 4; ++it)
    gload16(eb + (long)(q * 256 + it * 32 + rl) * SDIM + scs, &Ej[it * 2048 + dstc]);
  __syncthreads();

  bf16x8_t afrag[2];
  int ka = lr & 7;
  #pragma unroll
  for (int s = 0; s < 2; ++s)
    afrag[s] = *(const bf16x8_t*)&Ei[(wid * 16 + lr) * 64 + (((s * 4 + hi) ^ ka) * 8)];
  int rloc = wid * 16 + (hi << 2);
  float sqi[4];
  #pragma unroll
  for (int r = 0; r < 4; ++r) sqi[r] = sq[b * NN + i0 + rloc + r];
  float rs[4] = {0.f, 0.f, 0.f, 0.f};
  us* stripe = &Wt[wid * 2048];

  for (int jj = 0; jj < 2; ++jj) {
    int j0 = q * 256 + jj * 128;
    if (jj > 0) {
      __syncthreads();
      #pragma unroll
      for (int it = 0; it < 4; ++it)
        gload16(eb + (long)(j0 + it * 32 + rl) * SDIM + scs, &Ej[it * 2048 + dstc]);
      __syncthreads();
    }
    #pragma unroll
    for (int n = 0; n < 8; ++n) {
      f32x4_t g = {0.f, 0.f, 0.f, 0.f};
      #pragma unroll
      for (int s = 0; s < 2; ++s) {
        int rb = n * 16 + lr;
        bf16x8_t bfr = *(const bf16x8_t*)&Ej[rb * 64 + (((s * 4 + hi) ^ (rb & 7)) * 8)];
        g = __builtin_amdgcn_mfma_f32_16x16x32_bf16(afrag[s], bfr, g, 0, 0, 0);
      }
      float sqj = sq[b * NN + j0 + n * 16 + lr];
      #pragma unroll
      for (int r = 0; r < 4; ++r) {
        float d2 = sqi[r] + sqj - 2.0f * g[r];
        d2 = fmaxf(d2, 0.0f);
        float w = __expf(-d2);
        unsigned short wb = f2bf(w);
        rs[r] += bf2f(wb);
        int srow = (hi << 2) + r;
        stripe[srow * 128 + ((n ^ (srow & 3)) * 16) + lr] = wb;
      }
    }
    LGKM0();
    #pragma unroll
    for (int it = 0; it < 4; ++it) {
      int seg = it * 64 + lane;
      int row = seg >> 4, c8 = seg & 15;
      int c8s = c8 ^ ((row & 3) << 1);
      uint4 v = *(const uint4*)&stripe[row * 128 + c8s * 8];
      long gi = i0 + wid * 16 + row;
      *(uint4*)&wout[(long)b * NN * NN + gi * NN + j0 + c8 * 8] = v;
    }
  }
  #pragma unroll
  for (int off = 1; off < 16; off <<= 1) {
    #pragma unroll
    for (int r = 0; r < 4; ++r) rs[r] += __shfl_xor(rs[r], off);
  }
  if (lr == 0) {
    #pragma unroll
    for (int r = 0; r < 4; ++r)
      RS[(long)q * ROWS + b * NN + i0 + rloc + r] = rs[r];
  }
}

// ==== gemm1w2: FF1. SINGLE-WAVE barrier-free counted-vmcnt pipeline ===========
// 64x64 tile/wave, BK=32, per-wave dbuf 16 KB -> 10 blocks/CU. Loop:
// stage(t+1) [8 gload16, 16 in flight] -> s_waitcnt vmcnt(8) [tile t landed]
// -> 8x ds_read_b128 -> lgkmcnt(0)+sched_barrier (rule 18) -> 16 MFMA.
// Zero cross-wave hazards (private LDS). Content-swizzle key (row>>1)&3 ->
// 2-way bank aliasing only (free, m136). bf16 out, bias+GELU, repack->dwordx4.
__global__ __launch_bounds__(64) void gemm1w2(
    const unsigned short* __restrict__ A, const unsigned short* __restrict__ BT,
    unsigned short* __restrict__ Cout, const float* __restrict__ bias,
    int Nmat, int K) {
  __shared__ unsigned short As[2][2048];   // [buf][64*32]
  __shared__ unsigned short Bs[2][2048];
  int lane = threadIdx.x & 63;
  int lr = lane & 15, hi = lane >> 4;

  int gx = gridDim.x;
  int wg = blockIdx.y * gx + blockIdx.x;
  int nwg = gx * gridDim.y;
  if ((nwg & 7) == 0) wg = (wg & 7) * (nwg >> 3) + (wg >> 3);
  int bj = wg % gx, bi = wg / gx;
  int row0 = bi * 64, col0 = bj * 64;

  // staging: chunk = it*64+lane; row = chunk>>2 (4 chunks/row of 8 elems),
  // c = chunk&3, source col = (c ^ ((row>>1)&3)) * 8
  int r4 = lane >> 2;
  int c4 = lane & 3;
  const unsigned short* pA[4];
  const unsigned short* pB[4];
  #pragma unroll
  for (int it = 0; it < 4; ++it) {
    int row = it * 16 + r4;
    int sc = (c4 ^ ((row >> 1) & 3)) * 8;
    pA[it] = A + (long)(row0 + row) * K + sc;
    pB[it] = BT + (long)(col0 + row) * K + sc;
  }

  auto stage = [&](int buf) {
    #pragma unroll
    for (int it = 0; it < 4; ++it) {
      gload16(pA[it], &As[buf][it * 512]);
      gload16(pB[it], &Bs[buf][it * 512]);
      pA[it] += 32;
      pB[it] += 32;
    }
  };

  // fragment offsets: row = m*16+lr, k-chunk hi -> row*32 + ((hi^((row>>1)&3))*8)
  int offs[4];
  #pragma unroll
  for (int m = 0; m < 4; ++m) {
    int row = m * 16 + lr;
    offs[m] = row * 32 + ((hi ^ ((row >> 1) & 3)) * 8);
  }

  f32x4_t acc[4][4];
  #pragma unroll
  for (int m = 0; m < 4; ++m)
    #pragma unroll
    for (int n = 0; n < 4; ++n) acc[m][n] = (f32x4_t){0.f, 0.f, 0.f, 0.f};

  int nk = K >> 5;   // BK=32
  stage(0);          // 8 outstanding

  for (int t = 0; t < nk; ++t) {
    int cur = t & 1;
    if (t + 1 < nk) {
      stage(cur ^ 1);                                  // 16 outstanding
      asm volatile("s_waitcnt vmcnt(8)" ::: "memory"); // tile t landed; 8 fly
    } else {
      asm volatile("s_waitcnt vmcnt(0)" ::: "memory");
    }
    bf16x8_t a[4], b[4];
    #pragma unroll
    for (int m = 0; m < 4; ++m) a[m] = *(const bf16x8_t*)&As[cur][offs[m]];
    #pragma unroll
    for (int n = 0; n < 4; ++n) b[n] = *(const bf16x8_t*)&Bs[cur][offs[n]];
    asm volatile("s_waitcnt lgkmcnt(0)" ::: "memory");
    __builtin_amdgcn_sched_barrier(0);   // rule #18: pin MFMA after the wait
    #pragma unroll
    for (int m = 0; m < 4; ++m)
      #pragma unroll
      for (int n = 0; n < 4; ++n)
        acc[m][n] = MF(a[m], b[n], acc[m][n]);
  }

  // epilogue: bias + GELU -> 64x64 bf16 stripe in own LDS (As) -> dwordx4
  int cbase = col0 + lr;
  float bv[4];
  #pragma unroll
  for (int n = 0; n < 4; ++n) bv[n] = bias[cbase + n * 16];
  us* stripe = &As[0][0];   // 8 KB = 64x64 bf16
  #pragma unroll
  for (int m = 0; m < 4; ++m) {
    #pragma unroll
    for (int r = 0; r < 4; ++r) {
      int sr = m * 16 + hi * 4 + r;
      #pragma unroll
      for (int n = 0; n < 4; ++n)
        stripe[sr * 64 + ((n ^ (sr & 3)) * 16) + lr] =
            f2bf(gelu_fast(acc[m][n][r] + bv[n]));
    }
  }
  LGKM0();
  #pragma unroll
  for (int it = 0; it < 8; ++it) {
    int seg = it * 64 + lane;
    int sr = seg >> 3, c8 = seg & 7;
    int c8s = c8 ^ ((sr & 3) << 1);
    uint4 v = *(const uint4*)&stripe[sr * 64 + c8s * 8];
    long row = row0 + sr;
    *(uint4*)&Cout[row * Nmat + col0 + c8 * 8] = v;
  }
}

// ==== gemm128g: PV / FF2z. 128x128 tile, 4 waves of 64x64, split-phase ========
template <int EPI>
__global__ __launch_bounds__(256, 4) void gemm128g(
    const unsigned short* __restrict__ A, const unsigned short* __restrict__ BT,
    float* __restrict__ Cout, const float* __restrict__ bias,
    const float* __restrict__ resid, const float* __restrict__ RS,
    int Nmat, int K, long sA, long sB, long sC, long sR) {
  __shared__ unsigned short LB[16384];
  us* Asb = LB;
  us* Bsb = LB + 8192;
  int tid = threadIdx.x, lane = tid & 63;
  int lr = lane & 15, hi = lane >> 4;
  int wid = tid >> 6, wr = wid >> 1, wc = wid & 1;
  int bb = blockIdx.z;

  int gx = gridDim.x;
  int wg = blockIdx.y * gx + blockIdx.x;
  int nwg = gx * gridDim.y;
  if ((nwg & 7) == 0) wg = (wg & 7) * (nwg >> 3) + (wg >> 3);
  int bj = wg % gx, bi = wg / gx;
  int row0 = bi * 128, col0 = bj * 128;

  const unsigned short* Ab = A + (long)bb * sA;
  const unsigned short* Bb = BT + (long)bb * sB;

  int rl = tid >> 3;
  int scs = ((tid & 7) ^ (rl & 7)) * 8;
  const unsigned short* pA[4];
  const unsigned short* pB[4];
  #pragma unroll
  for (int it = 0; it < 4; ++it) {
    pA[it] = Ab + (long)(row0 + it * 32 + rl) * K + scs;
    pB[it] = Bb + (long)(col0 + it * 32 + rl) * K + scs;
  }
  int dstc = (tid & 192) * 8;

  int offA[4][2], offB[4][2];
  #pragma unroll
  for (int m = 0; m < 4; ++m) {
    #pragma unroll
    for (int s = 0; s < 2; ++s) {
      int ra = wr * 64 + m * 16 + lr;
      offA[m][s] = ra * 64 + (((s * 4 + hi) ^ (ra & 7)) * 8);
      int rb = wc * 64 + m * 16 + lr;
      offB[m][s] = rb * 64 + (((s * 4 + hi) ^ (rb & 7)) * 8);
    }
  }

  auto stage = [&]() {
    #pragma unroll
    for (int it = 0; it < 4; ++it) { gload16(pA[it], &Asb[it * 2048 + dstc]); pA[it] += 64; }
    #pragma unroll
    for (int it = 0; it < 4; ++it) { gload16(pB[it], &Bsb[it * 2048 + dstc]); pB[it] += 64; }
  };

  f32x4_t acc[4][4];
  #pragma unroll
  for (int m = 0; m < 4; ++m)
    #pragma unroll
    for (int n = 0; n < 4; ++n) acc[m][n] = (f32x4_t){0.f, 0.f, 0.f, 0.f};

  int nk = K >> 6;
  stage();

  for (int t = 0; t < nk; ++t) {
    __syncthreads();
    bf16x8_t a0[4], b0[4];
    #pragma unroll
    for (int m = 0; m < 4; ++m) a0[m] = *(const bf16x8_t*)&Asb[offA[m][0]];
    #pragma unroll
    for (int n = 0; n < 4; ++n) b0[n] = *(const bf16x8_t*)&Bsb[offB[n][0]];
    #pragma unroll
    for (int m = 0; m < 4; ++m)
      #pragma unroll
      for (int n = 0; n < 4; ++n)
        acc[m][n] = MF(a0[m], b0[n], acc[m][n]);
    bf16x8_t a1[4], b1[4];
    #pragma unroll
    for (int m = 0; m < 4; ++m) a1[m] = *(const bf16x8_t*)&Asb[offA[m][1]];
    #pragma unroll
    for (int n = 0; n < 4; ++n) b1[n] = *(const bf16x8_t*)&Bsb[offB[n][1]];
    __syncthreads();
    if (t + 1 < nk) stage();
    #pragma unroll
    for (int m = 0; m < 4; ++m)
      #pragma unroll
      for (int n = 0; n < 4; ++n)
        acc[m][n] = MF(a1[m], b1[n], acc[m][n]);
  }

  int rbase = row0 + wr * 64 + hi * 4;
  int cbase = col0 + wc * 64 + lr;
  float bv[4];
  #pragma unroll
  for (int n = 0; n < 4; ++n) bv[n] = (EPI == 2) ? bias[cbase + n * 16] : 0.f;
  #pragma unroll
  for (int m = 0; m < 4; ++m) {
    #pragma unroll
    for (int r = 0; r < 4; ++r) {
      int row = rbase + m * 16 + r;
      float ir = 0.f;
      if (EPI == 0) {
        long idx = (long)bb * sR + row;
        float den = 0.f;
        #pragma unroll
        for (int qq = 0; qq < 8; ++qq) den += RS[(long)qq * ROWS + idx];
        ir = 1.0f / den;
      }
      #pragma unroll
      for (int n = 0; n < 4; ++n) {
        int col = cbase + n * 16;
        long cidx = (long)bb * sC + (long)row * Nmat + col;
        if (EPI == 0) {
          Cout[cidx] = acc[m][n][r] * ir;
        } else {
          Cout[cidx] = acc[m][n][r] + bv[n] + resid[(long)bb * sR + (long)row * Nmat + col];
        }
      }
    }
  }
}

// ==== ff2s_part: FF2s split-K partial ==========================================
__global__ __launch_bounds__(256, 4) void ff2s_part(
    const unsigned short* __restrict__ A, const unsigned short* __restrict__ BT,
    float* __restrict__ SPART, int K) {
  __shared__ unsigned short As[128 * 64];
  __shared__ unsigned short Bs[64 * 64];
  int tid = threadIdx.x, lane = tid & 63;
  int lr = lane & 15, hi = lane >> 4;
  int wid = tid >> 6;
  int kz = blockIdx.z;
  int row0 = blockIdx.y * 128;

  int rl = tid >> 3;
  int scs = ((tid & 7) ^ (rl & 7)) * 8;
  long kbase = (long)kz * 512;
  const unsigned short* pA[4];
  #pragma unroll
  for (int it = 0; it < 4; ++it)
    pA[it] = A + (long)(row0 + it * 32 + rl) * K + kbase + scs;
  const unsigned short* pB[2];
  #pragma unroll
  for (int it = 0; it < 2; ++it)
    pB[it] = BT + (long)(it * 32 + rl) * K + kbase + scs;
  int dstc = (tid & 192) * 8;

  int offA[2][2], offB[4][2];
  #pragma unroll
  for (int m = 0; m < 2; ++m)
    #pragma unroll
    for (int s = 0; s < 2; ++s) {
      int ra = wid * 32 + m * 16 + lr;
      offA[m][s] = ra * 64 + (((s * 4 + hi) ^ (ra & 7)) * 8);
    }
  #pragma unroll
  for (int n = 0; n < 4; ++n)
    #pragma unroll
    for (int s = 0; s < 2; ++s) {
      int rb = n * 16 + lr;
      offB[n][s] = rb * 64 + (((s * 4 + hi) ^ (rb & 7)) * 8);
    }

  auto stage = [&]() {
    #pragma unroll
    for (int it = 0; it < 4; ++it) { gload16(pA[it], &As[it * 2048 + dstc]); pA[it] += 64; }
    #pragma unroll
    for (int it = 0; it < 2; ++it) { gload16(pB[it], &Bs[it * 2048 + dstc]); pB[it] += 64; }
  };

  f32x4_t acc[2][4];
  #pragma unroll
  for (int m = 0; m < 2; ++m)
    #pragma unroll
    for (int n = 0; n < 4; ++n) acc[m][n] = (f32x4_t){0.f, 0.f, 0.f, 0.f};

  stage();
  for (int t = 0; t < 8; ++t) {
    __syncthreads();
    bf16x8_t a0s0 = *(const bf16x8_t*)&As[offA[0][0]];
    bf16x8_t a1s0 = *(const bf16x8_t*)&As[offA[1][0]];
    bf16x8_t a0s1 = *(const bf16x8_t*)&As[offA[0][1]];
    bf16x8_t a1s1 = *(const bf16x8_t*)&As[offA[1][1]];
    bf16x8_t b0s0 = *(const bf16x8_t*)&Bs[offB[0][0]];
    bf16x8_t b1s0 = *(const bf16x8_t*)&Bs[offB[1][0]];
    bf16x8_t b2s0 = *(const bf16x8_t*)&Bs[offB[2][0]];
    bf16x8_t b3s0 = *(const bf16x8_t*)&Bs[offB[3][0]];
    bf16x8_t b0s1 = *(const bf16x8_t*)&Bs[offB[0][1]];
    bf16x8_t b1s1 = *(const bf16x8_t*)&Bs[offB[1][1]];
    bf16x8_t b2s1 = *(const bf16x8_t*)&Bs[offB[2][1]];
    bf16x8_t b3s1 = *(const bf16x8_t*)&Bs[offB[3][1]];
    __syncthreads();
    if (t + 1 < 8) stage();
    acc[0][0] = MF(a0s0, b0s0, acc[0][0]);
    acc[1][0] = MF(a1s0, b0s0, acc[1][0]);
    acc[0][1] = MF(a0s0, b1s0, acc[0][1]);
    acc[1][1] = MF(a1s0, b1s0, acc[1][1]);
    acc[0][2] = MF(a0s0, b2s0, acc[0][2]);
    acc[1][2] = MF(a1s0, b2s0, acc[1][2]);
    acc[0][3] = MF(a0s0, b3s0, acc[0][3]);
    acc[1][3] = MF(a1s0, b3s0, acc[1][3]);
    acc[0][0] = MF(a0s1, b0s1, acc[0][0]);
    acc[1][0] = MF(a1s1, b0s1, acc[1][0]);
    acc[0][1] = MF(a0s1, b1s1, acc[0][1]);
    acc[1][1] = MF(a1s1, b1s1, acc[1][1]);
    acc[0][2] = MF(a0s1, b2s1, acc[0][2]);
    acc[1][2] = MF(a1s1, b2s1, acc[1][2]);
    acc[0][3] = MF(a0s1, b3s1, acc[0][3]);
    acc[1][3] = MF(a1s1, b3s1, acc[1][3]);
  }

  float* outp = SPART + (long)kz * ROWS * SDIM;
  #pragma unroll
  for (int m = 0; m < 2; ++m) {
    #pragma unroll
    for (int r = 0; r < 4; ++r) {
      int row = row0 + wid * 32 + m * 16 + hi * 4 + r;
      #pragma unroll
      for (int n = 0; n < 4; ++n)
        outp[(long)row * SDIM + n * 16 + lr] = acc[m][n][r];
    }
  }
}

// ---- ff2s_red -----------------------------------------------------------------
__global__ __launch_bounds__(256) void ff2s_red(const float* __restrict__ SPART,
    const float* __restrict__ bias, const float* __restrict__ resid,
    float* __restrict__ out) {
  long idx = (long)blockIdx.x * 256 + threadIdx.x;
  int col = idx & (SDIM - 1);
  float v = SPART[idx] + SPART[(long)ROWS * SDIM + idx] +
            SPART[2L * ROWS * SDIM + idx] + SPART[3L * ROWS * SDIM + idx];
  out[idx] = v + bias[col] + resid[idx];
}

extern "C" void kernel_launch(void* const* d_in, const int* in_sizes, int n_in,
                              void* d_out, int out_size, void* d_ws, size_t ws_size,
                              hipStream_t stream) {
  (void)in_sizes; (void)n_in; (void)out_size; (void)ws_size;
  const float* in_z   = (const float*)d_in[0];
  const float* in_s   = (const float*)d_in[1];
  const float* lnz_sc = (const float*)d_in[2];
  const float* lnz_bi = (const float*)d_in[3];
  const float* lns_sc = (const float*)d_in[4];
  const float* lns_bi = (const float*)d_in[5];
  const float* Wz1 = (const float*)d_in[6];
  const float* bz1 = (const float*)d_in[7];
  const float* Wz2 = (const float*)d_in[8];
  const float* bz2 = (const float*)d_in[9];
  const float* Ws1 = (const float*)d_in[10];
  const float* bs1 = (const float*)d_in[11];
  const float* Ws2 = (const float*)d_in[12];
  const float* bs2 = (const float*)d_in[13];
  float* out_z = (float*)d_out;
  float* out_s = out_z + (long)ROWS * ZDIM;

  char* ws = (char*)d_ws;
  size_t off = 0;
  auto alloc = [&](size_t bytes) { void* p = ws + off; off += (bytes + 255) & ~(size_t)255; return p; };
  unsigned short* WH   = (unsigned short*)alloc((size_t)BATCH * NN * NN * 2); // w / h aliased
  unsigned short* ZT   = (unsigned short*)alloc((size_t)BATCH * ZDIM * NN * 2);
  unsigned short* XLN  = (unsigned short*)alloc((size_t)ROWS * ZDIM * 2);
  unsigned short* EBF  = (unsigned short*)alloc((size_t)ROWS * SDIM * 2);
  float* ZATT = (float*)alloc((size_t)ROWS * ZDIM * 4);
  float* ZBUF = (float*)alloc((size_t)ROWS * ZDIM * 4);
  float* SBUF = (float*)alloc((size_t)ROWS * SDIM * 4);
  float* SQ   = (float*)alloc((size_t)ROWS * 4);
  float* RS   = (float*)alloc((size_t)8 * ROWS * 4);
  float* SPART = (float*)alloc((size_t)4 * ROWS * SDIM * 4);
  unsigned short* W1Z = (unsigned short*)alloc((size_t)DEPTH * MLPD * ZDIM * 2);
  unsigned short* W2Z = (unsigned short*)alloc((size_t)DEPTH * ZDIM * MLPD * 2);
  unsigned short* W1S = (unsigned short*)alloc((size_t)DEPTH * MLPD * ZDIM * 2);
  unsigned short* W2S = (unsigned short*)alloc((size_t)DEPTH * SDIM * MLPD * 2);

  tconv_kernel<<<dim3(MLPD / 32, ZDIM / 32, DEPTH), dim3(32, 8), 0, stream>>>(
      Wz1, W1Z, ZDIM, MLPD, (long)ZDIM * MLPD, (long)MLPD * ZDIM);
  tconv_kernel<<<dim3(ZDIM / 32, MLPD / 32, DEPTH), dim3(32, 8), 0, stream>>>(
      Wz2, W2Z, MLPD, ZDIM, (long)MLPD * ZDIM, (long)ZDIM * MLPD);
  tconv_kernel<<<dim3(MLPD / 32, ZDIM / 32, DEPTH), dim3(32, 8), 0, stream>>>(
      Ws1, W1S, ZDIM, MLPD, (long)ZDIM * MLPD, (long)MLPD * ZDIM);
  tconv_kernel<<<dim3(SDIM / 32, MLPD / 32, DEPTH), dim3(32, 8), 0, stream>>>(
      Ws2, W2S, MLPD, SDIM, (long)MLPD * SDIM, (long)SDIM * MLPD);

  for (int L = 0; L < DEPTH; ++L) {
    const float* z_in = (L == 0) ? in_z : ZBUF;
    const float* s_in = (L == 0) ? in_s : SBUF;
    float* z_out = (L == DEPTH - 1) ? out_z : ZBUF;
    float* s_out = (L == DEPTH - 1) ? out_s : SBUF;

    conv_e_kernel<<<ROWS / 4, 256, 0, stream>>>(s_in, EBF, SQ);
    tconv_kernel<<<dim3(ZDIM / 32, NN / 32, BATCH), dim3(32, 8), 0, stream>>>(
        z_in, ZT, NN, ZDIM, (long)NN * ZDIM, (long)ZDIM * NN);
    attn_w_kernel<<<dim3(NN / 64, 8, BATCH), 256, 0, stream>>>(EBF, SQ, WH, RS);
    // z_att = (w @ z) / rowsum
    gemm128g<0><<<dim3(ZDIM / 128, NN / 128, BATCH), 256, 0, stream>>>(
        WH, ZT, ZATT, nullptr, nullptr, RS,
        ZDIM, NN, (long)NN * NN, (long)ZDIM * NN, (long)NN * ZDIM, NN);
    // z-FF
    ln_kernel<<<ROWS / 4, 256, 0, stream>>>(ZATT, lnz_sc + L * ZDIM, lnz_bi + L * ZDIM, XLN);
    gemm1w2<<<dim3(MLPD / 64, ROWS / 64, 1), 64, 0, stream>>>(
        XLN, W1Z + (long)L * MLPD * ZDIM, WH, bz1 + L * MLPD, MLPD, ZDIM);
    gemm128g<2><<<dim3(ZDIM / 128, ROWS / 128, 1), 256, 0, stream>>>(
        WH, W2Z + (long)L * ZDIM * MLPD, z_out, bz2 + L * ZDIM, ZATT, nullptr,
        ZDIM, MLPD, 0, 0, 0, 0);
    // s-FF
    ln_kernel<<<ROWS / 4, 256, 0, stream>>>(z_out, lns_sc + L * ZDIM, lns_bi + L * ZDIM, XLN);
    gemm1w2<<<dim3(MLPD / 64, ROWS / 64, 1), 64, 0, stream>>>(
        XLN, W1S + (long)L * MLPD * ZDIM, WH, bs1 + L * MLPD, MLPD, ZDIM);
    ff2s_part<<<dim3(1, ROWS / 128, 4), 256, 0, stream>>>(
        WH, W2S + (long)L * SDIM * MLPD, SPART, MLPD);
    ff2s_red<<<ROWS * SDIM / 256, 256, 0, stream>>>(
        SPART, bs2 + L * SDIM, s_in, s_out);
  }
}

// Round 18
// 942.095 us; speedup vs baseline: 1.2375x; 1.2375x over previous
//
#include <hip/hip_runtime.h>
#include <stdint.h>

#define DEPTH 4
#define BATCH 8
#define NN 2048
#define ZDIM 512
#define SDIM 64
#define MLPD 2048
#define ROWS (BATCH*NN)   // 16384

typedef __bf16 bf16x8_t __attribute__((ext_vector_type(8)));
typedef float f32x4_t __attribute__((ext_vector_type(4)));
typedef unsigned short us;

#define AS1 __attribute__((address_space(1)))
#define AS3 __attribute__((address_space(3)))

__device__ __forceinline__ void gload16(const void* g, void* l) {
  __builtin_amdgcn_global_load_lds((const AS1 void*)g, (AS3 void*)l, 16, 0, 0);
}

__device__ __forceinline__ unsigned short f2bf(float f) {
  union { float f; unsigned u; } v; v.f = f;
  unsigned u = v.u;
  unsigned r = (u + 0x7fffu + ((u >> 16) & 1u)) >> 16;
  return (unsigned short)r;
}
__device__ __forceinline__ float bf2f(unsigned short h) {
  union { unsigned u; float f; } v; v.u = ((unsigned)h) << 16;
  return v.f;
}

// tanh-form GELU
__device__ __forceinline__ float gelu_fast(float x) {
  float x2 = x * x;
  float q = fmaf(x2, -0.0713548162f, -1.5957691216f);
  float em = __expf(q * x);
  return x * __builtin_amdgcn_rcpf(1.0f + em);
}

#define LGKM0() do { asm volatile("s_waitcnt lgkmcnt(0)" ::: "memory"); \
                     __builtin_amdgcn_sched_barrier(0); } while (0)
#define MF(A_, B_, C_) __builtin_amdgcn_mfma_f32_16x16x32_bf16(A_, B_, C_, 0, 0, 0)

// ---- convert spatial embedding rows to bf16 + squared norms ------------------
__global__ __launch_bounds__(256) void conv_e_kernel(const float* __restrict__ s,
    unsigned short* __restrict__ ebf, float* __restrict__ sq) {
  int lane = threadIdx.x & 63;
  int row = blockIdx.x * 4 + (threadIdx.x >> 6);
  float x = s[(long)row * SDIM + lane];
  unsigned short v = f2bf(x);
  ebf[(long)row * SDIM + lane] = v;
  float xb = bf2f(v);
  float ss = xb * xb;
  #pragma unroll
  for (int off = 32; off > 0; off >>= 1) ss += __shfl_xor(ss, off);
  if (lane == 0) sq[row] = ss;
}

// ---- transpose + f32->bf16 ---------------------------------------------------
__global__ __launch_bounds__(256) void tconv_kernel(const float* __restrict__ in,
    unsigned short* __restrict__ out, int R, int C, long sIn, long sOut) {
  __shared__ float tile[32][33];
  int b = blockIdx.z;
  int c0 = blockIdx.x * 32, r0 = blockIdx.y * 32;
  int tx = threadIdx.x, ty = threadIdx.y;
  const float* ib = in + (long)b * sIn;
  unsigned short* ob = out + (long)b * sOut;
  #pragma unroll
  for (int i = 0; i < 32; i += 8)
    tile[ty + i][tx] = ib[(long)(r0 + ty + i) * C + c0 + tx];
  __syncthreads();
  #pragma unroll
  for (int i = 0; i < 32; i += 8)
    ob[(long)(c0 + ty + i) * R + r0 + tx] = f2bf(tile[tx][ty + i]);
}

// ---- LayerNorm over D=512 ----------------------------------------------------
__global__ __launch_bounds__(256) void ln_kernel(const float* __restrict__ x,
    const float* __restrict__ scale, const float* __restrict__ bias,
    unsigned short* __restrict__ y) {
  int lane = threadIdx.x & 63;
  long row = (long)blockIdx.x * 4 + (threadIdx.x >> 6);
  const float* xr = x + row * ZDIM + lane * 8;
  float4 v0 = *(const float4*)xr;
  float4 v1 = *(const float4*)(xr + 4);
  float xv[8] = {v0.x, v0.y, v0.z, v0.w, v1.x, v1.y, v1.z, v1.w};
  float s1 = 0.f, s2 = 0.f;
  #pragma unroll
  for (int k = 0; k < 8; ++k) { s1 += xv[k]; s2 += xv[k] * xv[k]; }
  #pragma unroll
  for (int off = 32; off > 0; off >>= 1) {
    s1 += __shfl_xor(s1, off);
    s2 += __shfl_xor(s2, off);
  }
  float mean = s1 * (1.0f / ZDIM);
  float var = s2 * (1.0f / ZDIM) - mean * mean;
  float rstd = rsqrtf(var + 1e-5f);
  const float* sc = scale + lane * 8;
  const float* bi = bias + lane * 8;
  alignas(16) unsigned short o[8];
  #pragma unroll
  for (int k = 0; k < 8; ++k)
    o[k] = f2bf((xv[k] - mean) * rstd * sc[k] + bi[k]);
  *(uint4*)(y + row * ZDIM + lane * 8) = *(const uint4*)o;
}

// ---- attention weights, 8-way j-split: 64 i-rows x 256 j-cols per block ------
// grid (NN/64, 8, BATCH); RS[q][b*NN+i] partial rowsums (q=0..7).
__global__ __launch_bounds__(256) void attn_w_kernel(const unsigned short* __restrict__ ebf,
    const float* __restrict__ sq, unsigned short* __restrict__ wout,
    float* __restrict__ RS) {
  __shared__ unsigned short Ei[4096];       // 64 x 64
  __shared__ unsigned short Ej[8192];       // 128 x 64
  __shared__ unsigned short Wt[8192];       // 4 waves x (16 x 128)
  int tid = threadIdx.x, lane = tid & 63, wid = tid >> 6;
  int lr = lane & 15, hi = lane >> 4;
  int q = blockIdx.y;
  int b = blockIdx.z;
  int i0 = blockIdx.x * 64;
  const unsigned short* eb = ebf + (long)b * NN * SDIM;

  int rl = tid >> 3;
  int scs = ((tid & 7) ^ (rl & 7)) * 8;
  int dstc = (tid & 192) * 8;

  #pragma unroll
  for (int it = 0; it < 2; ++it)
    gload16(eb + (long)(i0 + it * 32 + rl) * SDIM + scs, &Ei[it * 2048 + dstc]);
  #pragma unroll
  for (int it = 0; it < 4; ++it)
    gload16(eb + (long)(q * 256 + it * 32 + rl) * SDIM + scs, &Ej[it * 2048 + dstc]);
  __syncthreads();

  bf16x8_t afrag[2];
  int ka = lr & 7;
  #pragma unroll
  for (int s = 0; s < 2; ++s)
    afrag[s] = *(const bf16x8_t*)&Ei[(wid * 16 + lr) * 64 + (((s * 4 + hi) ^ ka) * 8)];
  int rloc = wid * 16 + (hi << 2);
  float sqi[4];
  #pragma unroll
  for (int r = 0; r < 4; ++r) sqi[r] = sq[b * NN + i0 + rloc + r];
  float rs[4] = {0.f, 0.f, 0.f, 0.f};
  us* stripe = &Wt[wid * 2048];

  for (int jj = 0; jj < 2; ++jj) {
    int j0 = q * 256 + jj * 128;
    if (jj > 0) {
      __syncthreads();
      #pragma unroll
      for (int it = 0; it < 4; ++it)
        gload16(eb + (long)(j0 + it * 32 + rl) * SDIM + scs, &Ej[it * 2048 + dstc]);
      __syncthreads();
    }
    #pragma unroll
    for (int n = 0; n < 8; ++n) {
      f32x4_t g = {0.f, 0.f, 0.f, 0.f};
      #pragma unroll
      for (int s = 0; s < 2; ++s) {
        int rb = n * 16 + lr;
        bf16x8_t bfr = *(const bf16x8_t*)&Ej[rb * 64 + (((s * 4 + hi) ^ (rb & 7)) * 8)];
        g = __builtin_amdgcn_mfma_f32_16x16x32_bf16(afrag[s], bfr, g, 0, 0, 0);
      }
      float sqj = sq[b * NN + j0 + n * 16 + lr];
      #pragma unroll
      for (int r = 0; r < 4; ++r) {
        float d2 = sqi[r] + sqj - 2.0f * g[r];
        d2 = fmaxf(d2, 0.0f);
        float w = __expf(-d2);
        unsigned short wb = f2bf(w);
        rs[r] += bf2f(wb);
        int srow = (hi << 2) + r;
        stripe[srow * 128 + ((n ^ (srow & 3)) * 16) + lr] = wb;
      }
    }
    LGKM0();
    #pragma unroll
    for (int it = 0; it < 4; ++it) {
      int seg = it * 64 + lane;
      int row = seg >> 4, c8 = seg & 15;
      int c8s = c8 ^ ((row & 3) << 1);
      uint4 v = *(const uint4*)&stripe[row * 128 + c8s * 8];
      long gi = i0 + wid * 16 + row;
      *(uint4*)&wout[(long)b * NN * NN + gi * NN + j0 + c8 * 8] = v;
    }
  }
  #pragma unroll
  for (int off = 1; off < 16; off <<= 1) {
    #pragma unroll
    for (int r = 0; r < 4; ++r) rs[r] += __shfl_xor(rs[r], off);
  }
  if (lr == 0) {
    #pragma unroll
    for (int r = 0; r < 4; ++r)
      RS[(long)q * ROWS + b * NN + i0 + rloc + r] = rs[r];
  }
}

// ==== gemm128ff: FF1. 128x128 tile, 4 waves of 64x64, split-phase =============
__global__ __launch_bounds__(256, 4) void gemm128ff(
    const unsigned short* __restrict__ A, const unsigned short* __restrict__ BT,
    unsigned short* __restrict__ Cout, const float* __restrict__ bias,
    int Nmat, int K) {
  __shared__ unsigned short LB[16384];
  us* Asb = LB;
  us* Bsb = LB + 8192;
  int tid = threadIdx.x, lane = tid & 63;
  int lr = lane & 15, hi = lane >> 4;
  int wid = tid >> 6, wr = wid >> 1, wc = wid & 1;

  int gx = gridDim.x;
  int wg = blockIdx.y * gx + blockIdx.x;
  int nwg = gx * gridDim.y;
  if ((nwg & 7) == 0) wg = (wg & 7) * (nwg >> 3) + (wg >> 3);
  int bj = wg % gx, bi = wg / gx;
  int row0 = bi * 128, col0 = bj * 128;

  int rl = tid >> 3;
  int scs = ((tid & 7) ^ (rl & 7)) * 8;
  const unsigned short* pA[4];
  const unsigned short* pB[4];
  #pragma unroll
  for (int it = 0; it < 4; ++it) {
    pA[it] = A + (long)(row0 + it * 32 + rl) * K + scs;
    pB[it] = BT + (long)(col0 + it * 32 + rl) * K + scs;
  }
  int dstc = (tid & 192) * 8;

  int offA[4][2], offB[4][2];
  #pragma unroll
  for (int m = 0; m < 4; ++m) {
    #pragma unroll
    for (int s = 0; s < 2; ++s) {
      int ra = wr * 64 + m * 16 + lr;
      offA[m][s] = ra * 64 + (((s * 4 + hi) ^ (ra & 7)) * 8);
      int rb = wc * 64 + m * 16 + lr;
      offB[m][s] = rb * 64 + (((s * 4 + hi) ^ (rb & 7)) * 8);
    }
  }

  auto stage = [&]() {
    #pragma unroll
    for (int it = 0; it < 4; ++it) { gload16(pA[it], &Asb[it * 2048 + dstc]); pA[it] += 64; }
    #pragma unroll
    for (int it = 0; it < 4; ++it) { gload16(pB[it], &Bsb[it * 2048 + dstc]); pB[it] += 64; }
  };

  f32x4_t acc[4][4];
  #pragma unroll
  for (int m = 0; m < 4; ++m)
    #pragma unroll
    for (int n = 0; n < 4; ++n) acc[m][n] = (f32x4_t){0.f, 0.f, 0.f, 0.f};

  int nk = K >> 6;
  stage();

  for (int t = 0; t < nk; ++t) {
    __syncthreads();
    bf16x8_t a0[4], b0[4];
    #pragma unroll
    for (int m = 0; m < 4; ++m) a0[m] = *(const bf16x8_t*)&Asb[offA[m][0]];
    #pragma unroll
    for (int n = 0; n < 4; ++n) b0[n] = *(const bf16x8_t*)&Bsb[offB[n][0]];
    #pragma unroll
    for (int m = 0; m < 4; ++m)
      #pragma unroll
      for (int n = 0; n < 4; ++n)
        acc[m][n] = MF(a0[m], b0[n], acc[m][n]);
    bf16x8_t a1[4], b1[4];
    #pragma unroll
    for (int m = 0; m < 4; ++m) a1[m] = *(const bf16x8_t*)&Asb[offA[m][1]];
    #pragma unroll
    for (int n = 0; n < 4; ++n) b1[n] = *(const bf16x8_t*)&Bsb[offB[n][1]];
    __syncthreads();
    if (t + 1 < nk) stage();
    #pragma unroll
    for (int m = 0; m < 4; ++m)
      #pragma unroll
      for (int n = 0; n < 4; ++n)
        acc[m][n] = MF(a1[m], b1[n], acc[m][n]);
  }

  int cbase = col0 + wc * 64 + lr;
  float bv[4];
  #pragma unroll
  for (int n = 0; n < 4; ++n) bv[n] = bias[cbase + n * 16];
  us* stripe = LB + wid * 4096;
  #pragma unroll
  for (int m = 0; m < 4; ++m) {
    #pragma unroll
    for (int r = 0; r < 4; ++r) {
      int sr = m * 16 + hi * 4 + r;
      #pragma unroll
      for (int n = 0; n < 4; ++n)
        stripe[sr * 64 + ((n ^ (sr & 3)) * 16) + lr] =
            f2bf(gelu_fast(acc[m][n][r] + bv[n]));
    }
  }
  LGKM0();
  #pragma unroll
  for (int it = 0; it < 8; ++it) {
    int seg = it * 64 + lane;
    int sr = seg >> 3, c8 = seg & 7;
    int c8s = c8 ^ ((sr & 3) << 1);
    uint4 v = *(const uint4*)&stripe[sr * 64 + c8s * 8];
    long row = row0 + wr * 64 + sr;
    *(uint4*)&Cout[row * Nmat + col0 + wc * 64 + c8 * 8] = v;
  }
}

// ==== gemm128g: PV / FF2z. 128x128 tile, 4 waves of 64x64, split-phase ========
// EPI 0: f32 out, scale by 1/sum(RS[0..7][row]).  EPI 2: f32 out, bias+resid.
template <int EPI>
__global__ __launch_bounds__(256, 4) void gemm128g(
    const unsigned short* __restrict__ A, const unsigned short* __restrict__ BT,
    float* __restrict__ Cout, const float* __restrict__ bias,
    const float* __restrict__ resid, const float* __restrict__ RS,
    int Nmat, int K, long sA, long sB, long sC, long sR) {
  __shared__ unsigned short LB[16384];
  us* Asb = LB;
  us* Bsb = LB + 8192;
  int tid = threadIdx.x, lane = tid & 63;
  int lr = lane & 15, hi = lane >> 4;
  int wid = tid >> 6, wr = wid >> 1, wc = wid & 1;
  int bb = blockIdx.z;

  int gx = gridDim.x;
  int wg = blockIdx.y * gx + blockIdx.x;
  int nwg = gx * gridDim.y;
  if ((nwg & 7) == 0) wg = (wg & 7) * (nwg >> 3) + (wg >> 3);
  int bj = wg % gx, bi = wg / gx;
  int row0 = bi * 128, col0 = bj * 128;

  const unsigned short* Ab = A + (long)bb * sA;
  const unsigned short* Bb = BT + (long)bb * sB;

  int rl = tid >> 3;
  int scs = ((tid & 7) ^ (rl & 7)) * 8;
  const unsigned short* pA[4];
  const unsigned short* pB[4];
  #pragma unroll
  for (int it = 0; it < 4; ++it) {
    pA[it] = Ab + (long)(row0 + it * 32 + rl) * K + scs;
    pB[it] = Bb + (long)(col0 + it * 32 + rl) * K + scs;
  }
  int dstc = (tid & 192) * 8;

  int offA[4][2], offB[4][2];
  #pragma unroll
  for (int m = 0; m < 4; ++m) {
    #pragma unroll
    for (int s = 0; s < 2; ++s) {
      int ra = wr * 64 + m * 16 + lr;
      offA[m][s] = ra * 64 + (((s * 4 + hi) ^ (ra & 7)) * 8);
      int rb = wc * 64 + m * 16 + lr;
      offB[m][s] = rb * 64 + (((s * 4 + hi) ^ (rb & 7)) * 8);
    }
  }

  auto stage = [&]() {
    #pragma unroll
    for (int it = 0; it < 4; ++it) { gload16(pA[it], &Asb[it * 2048 + dstc]); pA[it] += 64; }
    #pragma unroll
    for (int it = 0; it < 4; ++it) { gload16(pB[it], &Bsb[it * 2048 + dstc]); pB[it] += 64; }
  };

  f32x4_t acc[4][4];
  #pragma unroll
  for (int m = 0; m < 4; ++m)
    #pragma unroll
    for (int n = 0; n < 4; ++n) acc[m][n] = (f32x4_t){0.f, 0.f, 0.f, 0.f};

  int nk = K >> 6;
  stage();

  for (int t = 0; t < nk; ++t) {
    __syncthreads();
    bf16x8_t a0[4], b0[4];
    #pragma unroll
    for (int m = 0; m < 4; ++m) a0[m] = *(const bf16x8_t*)&Asb[offA[m][0]];
    #pragma unroll
    for (int n = 0; n < 4; ++n) b0[n] = *(const bf16x8_t*)&Bsb[offB[n][0]];
    #pragma unroll
    for (int m = 0; m < 4; ++m)
      #pragma unroll
      for (int n = 0; n < 4; ++n)
        acc[m][n] = MF(a0[m], b0[n], acc[m][n]);
    bf16x8_t a1[4], b1[4];
    #pragma unroll
    for (int m = 0; m < 4; ++m) a1[m] = *(const bf16x8_t*)&Asb[offA[m][1]];
    #pragma unroll
    for (int n = 0; n < 4; ++n) b1[n] = *(const bf16x8_t*)&Bsb[offB[n][1]];
    __syncthreads();
    if (t + 1 < nk) stage();
    #pragma unroll
    for (int m = 0; m < 4; ++m)
      #pragma unroll
      for (int n = 0; n < 4; ++n)
        acc[m][n] = MF(a1[m], b1[n], acc[m][n]);
  }

  int rbase = row0 + wr * 64 + hi * 4;
  int cbase = col0 + wc * 64 + lr;
  float bv[4];
  #pragma unroll
  for (int n = 0; n < 4; ++n) bv[n] = (EPI == 2) ? bias[cbase + n * 16] : 0.f;
  #pragma unroll
  for (int m = 0; m < 4; ++m) {
    #pragma unroll
    for (int r = 0; r < 4; ++r) {
      int row = rbase + m * 16 + r;
      float ir = 0.f;
      if (EPI == 0) {
        long idx = (long)bb * sR + row;
        float den = 0.f;
        #pragma unroll
        for (int qq = 0; qq < 8; ++qq) den += RS[(long)qq * ROWS + idx];
        ir = 1.0f / den;
      }
      #pragma unroll
      for (int n = 0; n < 4; ++n) {
        int col = cbase + n * 16;
        long cidx = (long)bb * sC + (long)row * Nmat + col;
        if (EPI == 0) {
          Cout[cidx] = acc[m][n][r] * ir;
        } else {
          Cout[cidx] = acc[m][n][r] + bv[n] + resid[(long)bb * sR + (long)row * Nmat + col];
        }
      }
    }
  }
}

// ==== ff2s_part: FF2s split-K partial. 128 M x 64 N tile, 4 waves of 32x64 ====
__global__ __launch_bounds__(256, 4) void ff2s_part(
    const unsigned short* __restrict__ A, const unsigned short* __restrict__ BT,
    float* __restrict__ SPART, int K) {
  __shared__ unsigned short As[128 * 64];   // 16 KB
  __shared__ unsigned short Bs[64 * 64];    // 8 KB
  int tid = threadIdx.x, lane = tid & 63;
  int lr = lane & 15, hi = lane >> 4;
  int wid = tid >> 6;
  int kz = blockIdx.z;
  int row0 = blockIdx.y * 128;

  int rl = tid >> 3;
  int scs = ((tid & 7) ^ (rl & 7)) * 8;
  long kbase = (long)kz * 512;
  const unsigned short* pA[4];
  #pragma unroll
  for (int it = 0; it < 4; ++it)
    pA[it] = A + (long)(row0 + it * 32 + rl) * K + kbase + scs;
  const unsigned short* pB[2];
  #pragma unroll
  for (int it = 0; it < 2; ++it)
    pB[it] = BT + (long)(it * 32 + rl) * K + kbase + scs;
  int dstc = (tid & 192) * 8;

  int offA[2][2], offB[4][2];
  #pragma unroll
  for (int m = 0; m < 2; ++m)
    #pragma unroll
    for (int s = 0; s < 2; ++s) {
      int ra = wid * 32 + m * 16 + lr;
      offA[m][s] = ra * 64 + (((s * 4 + hi) ^ (ra & 7)) * 8);
    }
  #pragma unroll
  for (int n = 0; n < 4; ++n)
    #pragma unroll
    for (int s = 0; s < 2; ++s) {
      int rb = n * 16 + lr;
      offB[n][s] = rb * 64 + (((s * 4 + hi) ^ (rb & 7)) * 8);
    }

  auto stage = [&]() {
    #pragma unroll
    for (int it = 0; it < 4; ++it) { gload16(pA[it], &As[it * 2048 + dstc]); pA[it] += 64; }
    #pragma unroll
    for (int it = 0; it < 2; ++it) { gload16(pB[it], &Bs[it * 2048 + dstc]); pB[it] += 64; }
  };

  f32x4_t acc[2][4];
  #pragma unroll
  for (int m = 0; m < 2; ++m)
    #pragma unroll
    for (int n = 0; n < 4; ++n) acc[m][n] = (f32x4_t){0.f, 0.f, 0.f, 0.f};

  stage();
  for (int t = 0; t < 8; ++t) {
    __syncthreads();
    bf16x8_t a0s0 = *(const bf16x8_t*)&As[offA[0][0]];
    bf16x8_t a1s0 = *(const bf16x8_t*)&As[offA[1][0]];
    bf16x8_t a0s1 = *(const bf16x8_t*)&As[offA[0][1]];
    bf16x8_t a1s1 = *(const bf16x8_t*)&As[offA[1][1]];
    bf16x8_t b0s0 = *(const bf16x8_t*)&Bs[offB[0][0]];
    bf16x8_t b1s0 = *(const bf16x8_t*)&Bs[offB[1][0]];
    bf16x8_t b2s0 = *(const bf16x8_t*)&Bs[offB[2][0]];
    bf16x8_t b3s0 = *(const bf16x8_t*)&Bs[offB[3][0]];
    bf16x8_t b0s1 = *(const bf16x8_t*)&Bs[offB[0][1]];
    bf16x8_t b1s1 = *(const bf16x8_t*)&Bs[offB[1][1]];
    bf16x8_t b2s1 = *(const bf16x8_t*)&Bs[offB[2][1]];
    bf16x8_t b3s1 = *(const bf16x8_t*)&Bs[offB[3][1]];
    __syncthreads();
    if (t + 1 < 8) stage();
    acc[0][0] = MF(a0s0, b0s0, acc[0][0]);
    acc[1][0] = MF(a1s0, b0s0, acc[1][0]);
    acc[0][1] = MF(a0s0, b1s0, acc[0][1]);
    acc[1][1] = MF(a1s0, b1s0, acc[1][1]);
    acc[0][2] = MF(a0s0, b2s0, acc[0][2]);
    acc[1][2] = MF(a1s0, b2s0, acc[1][2]);
    acc[0][3] = MF(a0s0, b3s0, acc[0][3]);
    acc[1][3] = MF(a1s0, b3s0, acc[1][3]);
    acc[0][0] = MF(a0s1, b0s1, acc[0][0]);
    acc[1][0] = MF(a1s1, b0s1, acc[1][0]);
    acc[0][1] = MF(a0s1, b1s1, acc[0][1]);
    acc[1][1] = MF(a1s1, b1s1, acc[1][1]);
    acc[0][2] = MF(a0s1, b2s1, acc[0][2]);
    acc[1][2] = MF(a1s1, b2s1, acc[1][2]);
    acc[0][3] = MF(a0s1, b3s1, acc[0][3]);
    acc[1][3] = MF(a1s1, b3s1, acc[1][3]);
  }

  float* outp = SPART + (long)kz * ROWS * SDIM;
  #pragma unroll
  for (int m = 0; m < 2; ++m) {
    #pragma unroll
    for (int r = 0; r < 4; ++r) {
      int row = row0 + wid * 32 + m * 16 + hi * 4 + r;
      #pragma unroll
      for (int n = 0; n < 4; ++n)
        outp[(long)row * SDIM + n * 16 + lr] = acc[m][n][r];
    }
  }
}

// ---- ff2s_red: sum 4 K-partials + bias + residual -> s_out -------------------
__global__ __launch_bounds__(256) void ff2s_red(const float* __restrict__ SPART,
    const float* __restrict__ bias, const float* __restrict__ resid,
    float* __restrict__ out) {
  long idx = (long)blockIdx.x * 256 + threadIdx.x;
  int col = idx & (SDIM - 1);
  float v = SPART[idx] + SPART[(long)ROWS * SDIM + idx] +
            SPART[2L * ROWS * SDIM + idx] + SPART[3L * ROWS * SDIM + idx];
  out[idx] = v + bias[col] + resid[idx];
}

extern "C" void kernel_launch(void* const* d_in, const int* in_sizes, int n_in,
                              void* d_out, int out_size, void* d_ws, size_t ws_size,
                              hipStream_t stream) {
  (void)in_sizes; (void)n_in; (void)out_size; (void)ws_size;
  const float* in_z   = (const float*)d_in[0];
  const float* in_s   = (const float*)d_in[1];
  const float* lnz_sc = (const float*)d_in[2];
  const float* lnz_bi = (const float*)d_in[3];
  const float* lns_sc = (const float*)d_in[4];
  const float* lns_bi = (const float*)d_in[5];
  const float* Wz1 = (const float*)d_in[6];
  const float* bz1 = (const float*)d_in[7];
  const float* Wz2 = (const float*)d_in[8];
  const float* bz2 = (const float*)d_in[9];
  const float* Ws1 = (const float*)d_in[10];
  const float* bs1 = (const float*)d_in[11];
  const float* Ws2 = (const float*)d_in[12];
  const float* bs2 = (const float*)d_in[13];
  float* out_z = (float*)d_out;
  float* out_s = out_z + (long)ROWS * ZDIM;

  char* ws = (char*)d_ws;
  size_t off = 0;
  auto alloc = [&](size_t bytes) { void* p = ws + off; off += (bytes + 255) & ~(size_t)255; return p; };
  unsigned short* WH   = (unsigned short*)alloc((size_t)BATCH * NN * NN * 2); // w / h aliased
  unsigned short* ZT   = (unsigned short*)alloc((size_t)BATCH * ZDIM * NN * 2);
  unsigned short* XLN  = (unsigned short*)alloc((size_t)ROWS * ZDIM * 2);
  unsigned short* EBF  = (unsigned short*)alloc((size_t)ROWS * SDIM * 2);
  float* ZATT = (float*)alloc((size_t)ROWS * ZDIM * 4);
  float* ZBUF = (float*)alloc((size_t)ROWS * ZDIM * 4);
  float* SBUF = (float*)alloc((size_t)ROWS * SDIM * 4);
  float* SQ   = (float*)alloc((size_t)ROWS * 4);
  float* RS   = (float*)alloc((size_t)8 * ROWS * 4);
  float* SPART = (float*)alloc((size_t)4 * ROWS * SDIM * 4);
  unsigned short* W1Z = (unsigned short*)alloc((size_t)DEPTH * MLPD * ZDIM * 2);
  unsigned short* W2Z = (unsigned short*)alloc((size_t)DEPTH * ZDIM * MLPD * 2);
  unsigned short* W1S = (unsigned short*)alloc((size_t)DEPTH * MLPD * ZDIM * 2);
  unsigned short* W2S = (unsigned short*)alloc((size_t)DEPTH * SDIM * MLPD * 2);

  tconv_kernel<<<dim3(MLPD / 32, ZDIM / 32, DEPTH), dim3(32, 8), 0, stream>>>(
      Wz1, W1Z, ZDIM, MLPD, (long)ZDIM * MLPD, (long)MLPD * ZDIM);
  tconv_kernel<<<dim3(ZDIM / 32, MLPD / 32, DEPTH), dim3(32, 8), 0, stream>>>(
      Wz2, W2Z, MLPD, ZDIM, (long)MLPD * ZDIM, (long)ZDIM * MLPD);
  tconv_kernel<<<dim3(MLPD / 32, ZDIM / 32, DEPTH), dim3(32, 8), 0, stream>>>(
      Ws1, W1S, ZDIM, MLPD, (long)ZDIM * MLPD, (long)MLPD * ZDIM);
  tconv_kernel<<<dim3(SDIM / 32, MLPD / 32, DEPTH), dim3(32, 8), 0, stream>>>(
      Ws2, W2S, MLPD, SDIM, (long)MLPD * SDIM, (long)SDIM * MLPD);

  for (int L = 0; L < DEPTH; ++L) {
    const float* z_in = (L == 0) ? in_z : ZBUF;
    const float* s_in = (L == 0) ? in_s : SBUF;
    float* z_out = (L == DEPTH - 1) ? out_z : ZBUF;
    float* s_out = (L == DEPTH - 1) ? out_s : SBUF;

    conv_e_kernel<<<ROWS / 4, 256, 0, stream>>>(s_in, EBF, SQ);
    tconv_kernel<<<dim3(ZDIM / 32, NN / 32, BATCH), dim3(32, 8), 0, stream>>>(
        z_in, ZT, NN, ZDIM, (long)NN * ZDIM, (long)ZDIM * NN);
    attn_w_kernel<<<dim3(NN / 64, 8, BATCH), 256, 0, stream>>>(EBF, SQ, WH, RS);
    // z_att = (w @ z) / rowsum
    gemm128g<0><<<dim3(ZDIM / 128, NN / 128, BATCH), 256, 0, stream>>>(
        WH, ZT, ZATT, nullptr, nullptr, RS,
        ZDIM, NN, (long)NN * NN, (long)ZDIM * NN, (long)NN * ZDIM, NN);
    // z-FF
    ln_kernel<<<ROWS / 4, 256, 0, stream>>>(ZATT, lnz_sc + L * ZDIM, lnz_bi + L * ZDIM, XLN);
    gemm128ff<<<dim3(MLPD / 128, ROWS / 128, 1), 256, 0, stream>>>(
        XLN, W1Z + (long)L * MLPD * ZDIM, WH, bz1 + L * MLPD, MLPD, ZDIM);
    gemm128g<2><<<dim3(ZDIM / 128, ROWS / 128, 1), 256, 0, stream>>>(
        WH, W2Z + (long)L * ZDIM * MLPD, z_out, bz2 + L * ZDIM, ZATT, nullptr,
        ZDIM, MLPD, 0, 0, 0, 0);
    // s-FF
    ln_kernel<<<ROWS / 4, 256, 0, stream>>>(z_out, lns_sc + L * ZDIM, lns_bi + L * ZDIM, XLN);
    gemm128ff<<<dim3(MLPD / 128, ROWS / 128, 1), 256, 0, stream>>>(
        XLN, W1S + (long)L * MLPD * ZDIM, WH, bs1 + L * MLPD, MLPD, ZDIM);
    ff2s_part<<<dim3(1, ROWS / 128, 4), 256, 0, stream>>>(
        WH, W2S + (long)L * SDIM * MLPD, SPART, MLPD);
    ff2s_red<<<ROWS * SDIM / 256, 256, 0, stream>>>(
        SPART, bs2 + L * SDIM, s_in, s_out);
  }
}